// Round 1
// baseline (198.173 us; speedup 1.0000x reference)
//
#include <hip/hip_runtime.h>
#include <hip/hip_bf16.h>

// y = x @ W.T, then 100x: y = Wx - y@M  ==>  y = x @ (W^T * S), S = sum_{k=0}^{100} (-M)^k
// rho(M)~0.5 => S ~= prod_{i=0}^{6} (I + A^(2^i)), A = -M (terms k>100 are ~2^-100, negligible in f32).
// Chain: P0 = W^T(I+A); P_{i} = P_{i-1}(I + T_i), T_i = A^(2^i) via repeated squaring.
// Final: one big bf16-MFMA GEMM y = x @ P (x converted to bf16 in regs, P pre-transposed to bf16).

typedef float f32x4 __attribute__((ext_vector_type(4)));
typedef __bf16 bf16x8 __attribute__((ext_vector_type(8)));

#define BATCH 65536
#define IN 512
#define OUT 256

// ---------------- chain kernels (tiny 256-wide matmuls, f32) ----------------
// Layouts: T [256][256] f32, P [512][256] f32, W input [256][512], M input [256][256].

// blocks 0..31: Tout = M*M (=A^2). blocks 32..95: Pout[i][j] = W[j][i] - sum_k W[k][i]*M[k][j]  (= W^T(I+A))
__global__ __launch_bounds__(256) void nsm_chain_first(const float* __restrict__ Wm,
                                                       const float* __restrict__ Mm,
                                                       float* __restrict__ Tout,
                                                       float* __restrict__ Pout) {
    __shared__ float sA[8][256];
    const int b = blockIdx.x, j = threadIdx.x;
    float acc[8];
    if (b < 32) {
        const int i0 = b * 8;
#pragma unroll
        for (int r = 0; r < 8; ++r) sA[r][j] = Mm[(i0 + r) * 256 + j];
        __syncthreads();
#pragma unroll
        for (int r = 0; r < 8; ++r) acc[r] = 0.f;
        for (int k4 = 0; k4 < 64; ++k4) {
            const int k = k4 * 4;
            const float b0 = Mm[(k + 0) * 256 + j], b1 = Mm[(k + 1) * 256 + j];
            const float b2 = Mm[(k + 2) * 256 + j], b3 = Mm[(k + 3) * 256 + j];
#pragma unroll
            for (int r = 0; r < 8; ++r) {
                const f32x4 av = *(const f32x4*)&sA[r][k];
                acc[r] += av[0] * b0 + av[1] * b1 + av[2] * b2 + av[3] * b3;
            }
        }
#pragma unroll
        for (int r = 0; r < 8; ++r) Tout[(i0 + r) * 256 + j] = acc[r];
    } else {
        const int i0 = (b - 32) * 8;  // row of P, 0..511
        // sA[r][k] = W[k][i0+r]; thread j loads k=j: 8 contiguous floats W[j*512 + i0 .. +8]
        const f32x4 w0 = *(const f32x4*)&Wm[j * IN + i0];
        const f32x4 w1 = *(const f32x4*)&Wm[j * IN + i0 + 4];
#pragma unroll
        for (int r = 0; r < 4; ++r) { sA[r][j] = w0[r]; sA[4 + r][j] = w1[r]; }
        __syncthreads();
#pragma unroll
        for (int r = 0; r < 8; ++r) acc[r] = sA[r][j];  // identity term: W[j][i0+r]
        for (int k4 = 0; k4 < 64; ++k4) {
            const int k = k4 * 4;
            const float b0 = Mm[(k + 0) * 256 + j], b1 = Mm[(k + 1) * 256 + j];
            const float b2 = Mm[(k + 2) * 256 + j], b3 = Mm[(k + 3) * 256 + j];
#pragma unroll
            for (int r = 0; r < 8; ++r) {
                const f32x4 av = *(const f32x4*)&sA[r][k];
                acc[r] -= av[0] * b0 + av[1] * b1 + av[2] * b2 + av[3] * b3;  // minus: A = -M
            }
        }
#pragma unroll
        for (int r = 0; r < 8; ++r) Pout[(i0 + r) * 256 + j] = acc[r];
    }
}

// blocks 0..31: Tout = Tin*Tin. blocks 32..95: Pout = Pin + Pin*Tin.
__global__ __launch_bounds__(256) void nsm_chain_mid(const float* __restrict__ Tin,
                                                     const float* __restrict__ Pin,
                                                     float* __restrict__ Tout,
                                                     float* __restrict__ Pout) {
    __shared__ float sA[8][256];
    const int b = blockIdx.x, j = threadIdx.x;
    float acc[8];
    if (b < 32) {
        const int i0 = b * 8;
#pragma unroll
        for (int r = 0; r < 8; ++r) sA[r][j] = Tin[(i0 + r) * 256 + j];
        __syncthreads();
#pragma unroll
        for (int r = 0; r < 8; ++r) acc[r] = 0.f;
        for (int k4 = 0; k4 < 64; ++k4) {
            const int k = k4 * 4;
            const float b0 = Tin[(k + 0) * 256 + j], b1 = Tin[(k + 1) * 256 + j];
            const float b2 = Tin[(k + 2) * 256 + j], b3 = Tin[(k + 3) * 256 + j];
#pragma unroll
            for (int r = 0; r < 8; ++r) {
                const f32x4 av = *(const f32x4*)&sA[r][k];
                acc[r] += av[0] * b0 + av[1] * b1 + av[2] * b2 + av[3] * b3;
            }
        }
#pragma unroll
        for (int r = 0; r < 8; ++r) Tout[(i0 + r) * 256 + j] = acc[r];
    } else {
        const int i0 = (b - 32) * 8;
#pragma unroll
        for (int r = 0; r < 8; ++r) sA[r][j] = Pin[(i0 + r) * 256 + j];
        __syncthreads();
#pragma unroll
        for (int r = 0; r < 8; ++r) acc[r] = sA[r][j];  // identity term
        for (int k4 = 0; k4 < 64; ++k4) {
            const int k = k4 * 4;
            const float b0 = Tin[(k + 0) * 256 + j], b1 = Tin[(k + 1) * 256 + j];
            const float b2 = Tin[(k + 2) * 256 + j], b3 = Tin[(k + 3) * 256 + j];
#pragma unroll
            for (int r = 0; r < 8; ++r) {
                const f32x4 av = *(const f32x4*)&sA[r][k];
                acc[r] += av[0] * b0 + av[1] * b1 + av[2] * b2 + av[3] * b3;
            }
        }
#pragma unroll
        for (int r = 0; r < 8; ++r) Pout[(i0 + r) * 256 + j] = acc[r];
    }
}

// grid 64: Pout = Pin + Pin*Tin  (last factor; no squaring needed)
__global__ __launch_bounds__(256) void nsm_chain_last(const float* __restrict__ Tin,
                                                      const float* __restrict__ Pin,
                                                      float* __restrict__ Pout) {
    __shared__ float sA[8][256];
    const int b = blockIdx.x, j = threadIdx.x;
    const int i0 = b * 8;
    float acc[8];
#pragma unroll
    for (int r = 0; r < 8; ++r) sA[r][j] = Pin[(i0 + r) * 256 + j];
    __syncthreads();
#pragma unroll
    for (int r = 0; r < 8; ++r) acc[r] = sA[r][j];
    for (int k4 = 0; k4 < 64; ++k4) {
        const int k = k4 * 4;
        const float b0 = Tin[(k + 0) * 256 + j], b1 = Tin[(k + 1) * 256 + j];
        const float b2 = Tin[(k + 2) * 256 + j], b3 = Tin[(k + 3) * 256 + j];
#pragma unroll
        for (int r = 0; r < 8; ++r) {
            const f32x4 av = *(const f32x4*)&sA[r][k];
            acc[r] += av[0] * b0 + av[1] * b1 + av[2] * b2 + av[3] * b3;
        }
    }
#pragma unroll
    for (int r = 0; r < 8; ++r) Pout[(i0 + r) * 256 + j] = acc[r];
}

// P [512][256] f32  ->  Pt [256][512] bf16 (transposed, row = output col, contiguous k)
__global__ __launch_bounds__(256) void nsm_transpose_cvt(const float* __restrict__ Pin,
                                                         __bf16* __restrict__ Ptb) {
    __shared__ float s[32][33];
    const int i0 = blockIdx.x * 32;  // 0..511 (16 tiles)
    const int j0 = blockIdx.y * 32;  // 0..255 (8 tiles)
    const int tx = threadIdx.x & 31, ty = threadIdx.x >> 5;  // ty 0..7
#pragma unroll
    for (int r = 0; r < 4; ++r) s[ty + r * 8][tx] = Pin[(i0 + ty + r * 8) * 256 + j0 + tx];
    __syncthreads();
#pragma unroll
    for (int r = 0; r < 4; ++r) Ptb[(size_t)(j0 + ty + r * 8) * IN + i0 + tx] = (__bf16)s[tx][ty + r * 8];
}

// ---------------- big GEMM: y[65536][256] = x[65536][512] @ P, via Pt[n][k] bf16 ----------------
// Block: 256 thr = 4 waves; block computes 64 rows x full 256 cols (x read once from HBM).
// Wave w: cols [64w, 64w+64). 4x4 MFMA tiles (16x16x32), acc f32x4 each.
// A-frag: lane holds x[row = m0+mt*16+(l&15)][k .. k+8), k = kk + 8*(l>>4)  (f32 -> bf16 in regs)
// B-frag: lane holds Pt[col = n0+nt*16+(l&15)][k .. k+8)  (contiguous 16B bf16 load)
// D: row = (l>>4)*4 + reg, col = l&15  (m89/m91-verified layout)
__global__ __launch_bounds__(256) void nsm_gemm_xP(const float* __restrict__ x,
                                                   const __bf16* __restrict__ Pt,
                                                   float* __restrict__ y) {
    const int tid = threadIdx.x;
    const int wave = tid >> 6;
    const int lane = tid & 63;
    const int l15 = lane & 15, lhi = lane >> 4;
    const int m0 = blockIdx.x * 64;
    const int n0 = wave * 64;

    f32x4 acc[4][4];
#pragma unroll
    for (int a = 0; a < 4; ++a)
#pragma unroll
        for (int c = 0; c < 4; ++c) acc[a][c] = (f32x4){0.f, 0.f, 0.f, 0.f};

    for (int kk = 0; kk < IN; kk += 32) {
        const int k = kk + lhi * 8;
        bf16x8 af[4], bf[4];
#pragma unroll
        for (int mt = 0; mt < 4; ++mt) {
            const float* px = x + (size_t)(m0 + mt * 16 + l15) * IN + k;
            const f32x4 f0 = *(const f32x4*)px;
            const f32x4 f1 = *(const f32x4*)(px + 4);
            bf16x8 t;
            t[0] = (__bf16)f0[0]; t[1] = (__bf16)f0[1]; t[2] = (__bf16)f0[2]; t[3] = (__bf16)f0[3];
            t[4] = (__bf16)f1[0]; t[5] = (__bf16)f1[1]; t[6] = (__bf16)f1[2]; t[7] = (__bf16)f1[3];
            af[mt] = t;
        }
#pragma unroll
        for (int nt = 0; nt < 4; ++nt) {
            bf[nt] = *(const bf16x8*)(Pt + (size_t)(n0 + nt * 16 + l15) * IN + k);
        }
#pragma unroll
        for (int mt = 0; mt < 4; ++mt)
#pragma unroll
            for (int nt = 0; nt < 4; ++nt)
                acc[mt][nt] = __builtin_amdgcn_mfma_f32_16x16x32_bf16(af[mt], bf[nt], acc[mt][nt], 0, 0, 0);
    }

#pragma unroll
    for (int mt = 0; mt < 4; ++mt) {
#pragma unroll
        for (int nt = 0; nt < 4; ++nt) {
            const int col = n0 + nt * 16 + l15;
            const int row = m0 + mt * 16 + lhi * 4;
#pragma unroll
            for (int r = 0; r < 4; ++r) y[(size_t)(row + r) * OUT + col] = acc[mt][nt][r];
        }
    }
}

extern "C" void kernel_launch(void* const* d_in, const int* in_sizes, int n_in,
                              void* d_out, int out_size, void* d_ws, size_t ws_size,
                              hipStream_t stream) {
    const float* x = (const float*)d_in[0];   // [65536][512]
    const float* W = (const float*)d_in[1];   // [256][512]
    const float* M = (const float*)d_in[2];   // [256][256]
    float* y = (float*)d_out;                 // [65536][256]

    char* ws = (char*)d_ws;
    float* Ta = (float*)(ws);                   // 256 KB
    float* Tb = (float*)(ws + (256 << 10));     // 256 KB
    float* Pa = (float*)(ws + (512 << 10));     // 512 KB
    float* Pb = (float*)(ws + (1024 << 10));    // 512 KB
    __bf16* Ptb = (__bf16*)(ws + (1536 << 10)); // 256 KB (bf16 [256][512])

    // chain: P = W^T * prod_{i=0..6} (I + A^(2^i)),  A = -M
    nsm_chain_first<<<96, 256, 0, stream>>>(W, M, Ta, Pa);        // T1=A^2 (Ta), P0 (Pa)
    nsm_chain_mid<<<96, 256, 0, stream>>>(Ta, Pa, Tb, Pb);        // T2, P1
    nsm_chain_mid<<<96, 256, 0, stream>>>(Tb, Pb, Ta, Pa);        // T3, P2
    nsm_chain_mid<<<96, 256, 0, stream>>>(Ta, Pa, Tb, Pb);        // T4, P3
    nsm_chain_mid<<<96, 256, 0, stream>>>(Tb, Pb, Ta, Pa);        // T5, P4
    nsm_chain_mid<<<96, 256, 0, stream>>>(Ta, Pa, Tb, Pb);        // T6, P5
    nsm_chain_last<<<64, 256, 0, stream>>>(Tb, Pb, Pa);           // P6 = P5(I+T6) -> Pa
    nsm_transpose_cvt<<<dim3(16, 8), 256, 0, stream>>>(Pa, Ptb);  // Pt bf16 [256][512]
    nsm_gemm_xP<<<BATCH / 64, 256, 0, stream>>>(x, Ptb, y);       // y = x @ P
}

// Round 2
// 92.591 us; speedup vs baseline: 2.1403x; 2.1403x over previous
//
#include <hip/hip_runtime.h>
#include <hip/hip_bf16.h>

// y = x @ (W^T * S), S = sum_{k=0}^{100} (-M)^k ~= prod_{i=0}^{5} (I + A^(2^i)), A = -M
// (64 terms; ||M^64|| ~ 1e-17 << f32 eps). Chain: 6 k-parallel launches, last one
// writes P transposed in bf16. Final: one bf16-MFMA GEMM with global_load_lds dbuf.

typedef float f32x4 __attribute__((ext_vector_type(4)));
typedef __bf16 bf16x8 __attribute__((ext_vector_type(8)));

#define IN 512
#define OUT 256
#define BATCH 65536

#define GLOAD_LDS16(gp, lp)                                                              \
    __builtin_amdgcn_global_load_lds((const __attribute__((address_space(1))) void*)(gp), \
                                     (__attribute__((address_space(3))) void*)(lp), 16, 0, 0)

// ---------------- chain: k-parallel small matmuls ----------------
// Block: 1024 thr, thread (j = t&255, q = t>>8). q splits k into 4x64.
// acc[8] = rows i0..i0+8 partial sums over k in [64q, 64q+64). LDS reduce after.

__device__ __forceinline__ void chain_core(const float (*sA)[256], const float* __restrict__ B,
                                           int j, int q, float acc[8]) {
#pragma unroll
    for (int r = 0; r < 8; ++r) acc[r] = 0.f;
    const int kbase = q * 64;
#pragma unroll
    for (int it = 0; it < 16; ++it) {
        const int k = kbase + it * 4;
        const float b0 = B[(k + 0) * 256 + j];
        const float b1 = B[(k + 1) * 256 + j];
        const float b2 = B[(k + 2) * 256 + j];
        const float b3 = B[(k + 3) * 256 + j];
#pragma unroll
        for (int r = 0; r < 8; ++r) {
            const f32x4 av = *(const f32x4*)&sA[r][k];
            acc[r] += av[0] * b0 + av[1] * b1 + av[2] * b2 + av[3] * b3;
        }
    }
}

// blocks 0..31: Tout = Tin_sq (rows of Bmat * Bmat... here A-rows = Bmat rows).
// blocks 32..95: Pout = init +/- Arows*Bmat. first=1: A = W^T (strided), sign -1. else Pin, +1.
__global__ __launch_bounds__(1024) void nsm_chain_step(const float* __restrict__ Bmat,  // [256][256] (M or T_i)
                                                       const float* __restrict__ Pin,   // W [256][512] if first, else P [512][256]
                                                       float* __restrict__ Tout,
                                                       float* __restrict__ Pout,
                                                       const int first) {
    __shared__ float sA[8][256];
    __shared__ float ws[4][8][256];
    const int t = threadIdx.x, j = t & 255, q = t >> 8, b = blockIdx.x;
    float acc[8];
    const bool isT = (b < 32);
    if (isT) {
        const int i0 = b * 8;
        sA[2 * q][j]     = Bmat[(i0 + 2 * q) * 256 + j];
        sA[2 * q + 1][j] = Bmat[(i0 + 2 * q + 1) * 256 + j];
    } else {
        const int i0 = (b - 32) * 8;
        if (first) {  // sA[r][k] = W[k][i0+r] = W[k*512 + i0 + r]
            sA[2 * q][j]     = Pin[j * IN + i0 + 2 * q];
            sA[2 * q + 1][j] = Pin[j * IN + i0 + 2 * q + 1];
        } else {
            sA[2 * q][j]     = Pin[(i0 + 2 * q) * 256 + j];
            sA[2 * q + 1][j] = Pin[(i0 + 2 * q + 1) * 256 + j];
        }
    }
    __syncthreads();
    chain_core(sA, Bmat, j, q, acc);
#pragma unroll
    for (int r = 0; r < 8; ++r) ws[q][r][j] = acc[r];
    __syncthreads();
#pragma unroll
    for (int d = 0; d < 2; ++d) {
        const int r = 2 * q + d;
        const float v = ws[0][r][j] + ws[1][r][j] + ws[2][r][j] + ws[3][r][j];
        if (isT) {
            const int i0 = b * 8;
            Tout[(i0 + r) * 256 + j] = v;  // T^2 (sign cancels for A = -M)
        } else {
            const int i0 = (b - 32) * 8;
            // init = sA[r][j]: W[j][i0+r] if first (== W^T[i0+r][j]), else Pin[i0+r][j]
            Pout[(i0 + r) * 256 + j] = first ? (sA[r][j] - v) : (sA[r][j] + v);
        }
    }
}

// grid 64: Ptb[j][i] = bf16( Pin[i][j] + (Pin*Bmat)[i][j] )  (last factor + transpose + cvt)
__global__ __launch_bounds__(1024) void nsm_chain_last(const float* __restrict__ Bmat,
                                                       const float* __restrict__ Pin,
                                                       __bf16* __restrict__ Ptb) {
    __shared__ float sA[8][256];
    __shared__ float ws[4][8][256];
    const int t = threadIdx.x, j = t & 255, q = t >> 8, b = blockIdx.x;
    const int i0 = b * 8;
    float acc[8];
    sA[2 * q][j]     = Pin[(i0 + 2 * q) * 256 + j];
    sA[2 * q + 1][j] = Pin[(i0 + 2 * q + 1) * 256 + j];
    __syncthreads();
    chain_core(sA, Bmat, j, q, acc);
#pragma unroll
    for (int r = 0; r < 8; ++r) ws[q][r][j] = acc[r];
    __syncthreads();
#pragma unroll
    for (int d = 0; d < 2; ++d) {
        const int r = 2 * q + d;
        const float v = ws[0][r][j] + ws[1][r][j] + ws[2][r][j] + ws[3][r][j];
        Ptb[(size_t)j * IN + i0 + r] = (__bf16)(sA[r][j] + v);
    }
}

// ---------------- big GEMM: y[65536][256] = x[65536][512] @ P, Pt[n][k] bf16 ----------------
// Block 256 thr / 4 waves, 64 rows x 256 cols; wave w -> cols [64w,64w+64), 4x4 16x16x32 tiles.
// Double-buffered LDS staging via global_load_lds(16B):
//   xs [buf][64][32] f32 : 16B chunk c stores global chunk c ^ (row&7)   (pre-swizzled src)
//   ps [buf][256][32] bf16: 16B chunk c stores global chunk c ^ ((col>>1)&3)
// Frag reads apply the same XOR -> ~2-way banks. A-frags cvt f32->bf16 in regs.
__global__ __launch_bounds__(256) void nsm_gemm_xP(const float* __restrict__ x,
                                                   const __bf16* __restrict__ Pt,
                                                   float* __restrict__ y) {
    __shared__ float xs[2][64][32];     // 2 x 8 KB
    __shared__ __bf16 ps[2][256][32];   // 2 x 16 KB
    const int tid = threadIdx.x;
    const int wave = tid >> 6, lane = tid & 63;
    const int l15 = lane & 15, lhi = lane >> 4;
    const int m0 = blockIdx.x * 64;
    const int n0 = wave * 64;

    f32x4 acc[4][4];
#pragma unroll
    for (int a = 0; a < 4; ++a)
#pragma unroll
        for (int c = 0; c < 4; ++c) acc[a][c] = (f32x4){0.f, 0.f, 0.f, 0.f};

    auto stage = [&](int buf, int kk) {
        // x tile: 8 KB = 8 x 1KB calls; wave w covers rows [16w, 16w+16) in 2 calls
#pragma unroll
        for (int i = 0; i < 2; ++i) {
            const int r0 = wave * 16 + i * 8;
            const int row = r0 + (lane >> 3);
            const int g = (lane & 7) ^ (row & 7);
            const float* src = x + (size_t)(m0 + row) * IN + kk + g * 4;
            GLOAD_LDS16(src, &xs[buf][r0][0]);
        }
        // Pt tile: 16 KB = 16 x 1KB calls; wave w covers cols [64w, 64w+64) in 4 calls
#pragma unroll
        for (int i = 0; i < 4; ++i) {
            const int c0 = wave * 64 + i * 16;
            const int col = c0 + (lane >> 2);
            const int g = (lane & 3) ^ ((col >> 1) & 3);
            const __bf16* src = Pt + (size_t)col * IN + kk + g * 8;
            GLOAD_LDS16(src, &ps[buf][c0][0]);
        }
    };

    auto compute = [&](int buf) {
        bf16x8 af[4], bfr[4];
#pragma unroll
        for (int mt = 0; mt < 4; ++mt) {
            const int row = mt * 16 + l15;
            const int c0 = (2 * lhi) ^ (row & 7);
            const int c1 = (2 * lhi + 1) ^ (row & 7);
            const f32x4 f0 = *(const f32x4*)&xs[buf][row][c0 * 4];
            const f32x4 f1 = *(const f32x4*)&xs[buf][row][c1 * 4];
            bf16x8 tt;
            tt[0] = (__bf16)f0[0]; tt[1] = (__bf16)f0[1]; tt[2] = (__bf16)f0[2]; tt[3] = (__bf16)f0[3];
            tt[4] = (__bf16)f1[0]; tt[5] = (__bf16)f1[1]; tt[6] = (__bf16)f1[2]; tt[7] = (__bf16)f1[3];
            af[mt] = tt;
        }
#pragma unroll
        for (int nt = 0; nt < 4; ++nt) {
            const int col = n0 + nt * 16 + l15;
            const int cs = lhi ^ ((col >> 1) & 3);
            bfr[nt] = *(const bf16x8*)&ps[buf][col][cs * 8];
        }
#pragma unroll
        for (int mt = 0; mt < 4; ++mt)
#pragma unroll
            for (int nt = 0; nt < 4; ++nt)
                acc[mt][nt] = __builtin_amdgcn_mfma_f32_16x16x32_bf16(af[mt], bfr[nt], acc[mt][nt], 0, 0, 0);
    };

    stage(0, 0);
    __syncthreads();  // drains vmcnt(0): buf0 ready
    for (int t = 0; t < 16; ++t) {
        const int cur = t & 1;
        if (t < 15) stage(cur ^ 1, (t + 1) * 32);
        compute(cur);
        __syncthreads();  // staging complete + all reads of cur done
    }

#pragma unroll
    for (int mt = 0; mt < 4; ++mt) {
#pragma unroll
        for (int nt = 0; nt < 4; ++nt) {
            const int col = n0 + nt * 16 + l15;
            const int row = m0 + mt * 16 + lhi * 4;
#pragma unroll
            for (int r = 0; r < 4; ++r) y[(size_t)(row + r) * OUT + col] = acc[mt][nt][r];
        }
    }
}

extern "C" void kernel_launch(void* const* d_in, const int* in_sizes, int n_in,
                              void* d_out, int out_size, void* d_ws, size_t ws_size,
                              hipStream_t stream) {
    const float* x = (const float*)d_in[0];   // [65536][512]
    const float* W = (const float*)d_in[1];   // [256][512]
    const float* M = (const float*)d_in[2];   // [256][256]
    float* y = (float*)d_out;                 // [65536][256]

    char* ws = (char*)d_ws;
    float* Ta = (float*)(ws);                   // 256 KB
    float* Tb = (float*)(ws + (256 << 10));     // 256 KB
    float* Pa = (float*)(ws + (512 << 10));     // 512 KB
    float* Pb = (float*)(ws + (1024 << 10));    // 512 KB
    __bf16* Ptb = (__bf16*)(ws + (1536 << 10)); // 256 KB  bf16 [256][512]

    // chain: P = W^T * prod_{i=0..5} (I + A^(2^i)), A = -M  (sum_{k=0}^{63} A^k)
    nsm_chain_step<<<96, 1024, 0, stream>>>(M, W, Ta, Pa, 1);   // T1=A^2, P0=W^T(I+A)
    nsm_chain_step<<<96, 1024, 0, stream>>>(Ta, Pa, Tb, Pb, 0); // T2=A^4,  P1=P0(I+A^2)
    nsm_chain_step<<<96, 1024, 0, stream>>>(Tb, Pb, Ta, Pa, 0); // T3=A^8,  P2=P1(I+A^4)
    nsm_chain_step<<<96, 1024, 0, stream>>>(Ta, Pa, Tb, Pb, 0); // T4=A^16, P3=P2(I+A^8)
    nsm_chain_step<<<96, 1024, 0, stream>>>(Tb, Pb, Ta, Pa, 0); // T5=A^32, P4=P3(I+A^16)
    nsm_chain_last<<<64, 1024, 0, stream>>>(Ta, Pa, Ptb);       // Ptb = bf16((P4(I+A^32))^T)
    nsm_gemm_xP<<<BATCH / 64, 256, 0, stream>>>(x, Ptb, y);     // y = x @ P
}